// Round 2
// baseline (8655.943 us; speedup 1.0000x reference)
//
#include <hip/hip_runtime.h>

#define TT 512
#define XD 512
#define HH 1024
#define NGROUP 4
#define BLK_PER_G 64
#define MROWS 16

typedef __attribute__((ext_vector_type(8))) _Float16 h8;
typedef __attribute__((ext_vector_type(4))) float f4;

__global__ __launch_bounds__(256, 1) void lstm_fused(
    const float* __restrict__ X,
    const float* __restrict__ Whi, const float* __restrict__ Wxi, const float* __restrict__ bi_p,
    const float* __restrict__ Whf, const float* __restrict__ Wxf, const float* __restrict__ bf_p,
    const float* __restrict__ Who, const float* __restrict__ Wxo, const float* __restrict__ bo_p,
    const float* __restrict__ Whz, const float* __restrict__ Wxz, const float* __restrict__ bz_p,
    float* __restrict__ out,
    int* __restrict__ flags)          // [NGROUP][BLK_PER_G] in d_ws
{
    __shared__ float red[3][4][2][64][2];  // partials from waves 1..3

    const int tid  = threadIdx.x;
    const int wave = tid >> 6;
    const int lane = tid & 63;
    const int ln   = lane & 15;   // N col (B/C frags) / M row (A frags)
    const int lq   = lane >> 4;   // quad 0..3

    const int blk = blockIdx.x;
    const int g   = blk & 3;      // group (batch slice)
    const int j   = blk >> 2;     // 0..63 column-slice within group
    const int colbase = j * 16;
    const int rowbase = g * MROWS;
    const int col = colbase + ln;

    const float* Wh[4]   = {Whi, Whf, Who, Whz};
    const float* Wx[4]   = {Wxi, Wxf, Wxo, Wxz};
    const float* bias[4] = {bi_p, bf_p, bo_p, bz_p};

    // ---- one-time: weights -> f16 B-fragments pinned in VGPRs ----
    // B-frag (16x16x32): lane holds B[k = lq*8 + q][n = ln] per K-tile.
    h8 bh[4][8];   // Wh: this wave's K slice [wave*256, wave*256+256)
    h8 bx[4][4];   // Wx: this wave's K slice [wave*128, wave*128+128)
#pragma unroll
    for (int gi = 0; gi < 4; ++gi) {
        const float* W = Wh[gi];
#pragma unroll
        for (int kt = 0; kt < 8; ++kt) {
            const int k0 = wave * 256 + kt * 32 + lq * 8;
            h8 f;
#pragma unroll
            for (int q = 0; q < 8; ++q) f[q] = (_Float16)W[(k0 + q) * HH + col];
            bh[gi][kt] = f;
        }
        const float* Wq = Wx[gi];
#pragma unroll
        for (int kt = 0; kt < 4; ++kt) {
            const int k0 = wave * 128 + kt * 32 + lq * 8;
            h8 f;
#pragma unroll
            for (int q = 0; q < 8; ++q) f[q] = (_Float16)Wq[(k0 + q) * HH + col];
            bx[gi][kt] = f;
        }
    }
    float bsum[4];
#pragma unroll
    for (int gi = 0; gi < 4; ++gi) bsum[gi] = bias[gi][col];

    float cprev[4] = {0.f, 0.f, 0.f, 0.f};

    const float* Xrow   = X   + (size_t)(rowbase + ln) * (TT * XD);
    const float* OutRow = out + (size_t)(rowbase + ln) * (TT * HH);

    for (int t = 0; t < TT; ++t) {
        // ---- X A-fragments for this step (no dependence on barrier) ----
        h8 ax[4];
#pragma unroll
        for (int kt = 0; kt < 4; ++kt) {
            const float4* xp = (const float4*)(Xrow + t * XD + wave * 128 + kt * 32 + lq * 8);
            float4 a = xp[0], b2 = xp[1];
            h8 f;
            f[0] = (_Float16)a.x;  f[1] = (_Float16)a.y;
            f[2] = (_Float16)a.z;  f[3] = (_Float16)a.w;
            f[4] = (_Float16)b2.x; f[5] = (_Float16)b2.y;
            f[6] = (_Float16)b2.z; f[7] = (_Float16)b2.w;
            ax[kt] = f;
        }

        f4 acc[4];
#pragma unroll
        for (int gi = 0; gi < 4; ++gi) acc[gi] = (f4){0.f, 0.f, 0.f, 0.f};

        // x-part MFMAs first (independent of h_{t-1})
#pragma unroll
        for (int kt = 0; kt < 4; ++kt)
#pragma unroll
            for (int gi = 0; gi < 4; ++gi)
                acc[gi] = __builtin_amdgcn_mfma_f32_16x16x32_f16(ax[kt], bx[gi][kt], acc[gi], 0, 0, 0);

        if (t > 0) {
            // group barrier: wait until all 64 blocks published h_{t-1}
            int* fl = flags + g * BLK_PER_G;
            while (true) {
                int v = __hip_atomic_load(fl + lane, __ATOMIC_RELAXED, __HIP_MEMORY_SCOPE_AGENT);
                if (__all(v >= t)) break;
                __builtin_amdgcn_s_sleep(2);
            }
            __builtin_amdgcn_fence(__ATOMIC_ACQUIRE, "agent");

            // h_{t-1} lives in out[:, t-1, :] (f32) — convert to f16 A-frags
            const float* hb = OutRow + (size_t)(t - 1) * HH;
            h8 ah[8];
#pragma unroll
            for (int kt = 0; kt < 8; ++kt) {
                const float4* hp = (const float4*)(hb + wave * 256 + kt * 32 + lq * 8);
                float4 a = hp[0], b2 = hp[1];
                h8 f;
                f[0] = (_Float16)a.x;  f[1] = (_Float16)a.y;
                f[2] = (_Float16)a.z;  f[3] = (_Float16)a.w;
                f[4] = (_Float16)b2.x; f[5] = (_Float16)b2.y;
                f[6] = (_Float16)b2.z; f[7] = (_Float16)b2.w;
                ah[kt] = f;
            }
#pragma unroll
            for (int kt = 0; kt < 8; ++kt)
#pragma unroll
                for (int gi = 0; gi < 4; ++gi)
                    acc[gi] = __builtin_amdgcn_mfma_f32_16x16x32_f16(ah[kt], bh[gi][kt], acc[gi], 0, 0, 0);
        }

        // ---- cross-wave K reduction through LDS ----
        if (wave > 0) {
#pragma unroll
            for (int gi = 0; gi < 4; ++gi) {
                red[wave - 1][gi][0][lane][0] = acc[gi][0];
                red[wave - 1][gi][0][lane][1] = acc[gi][1];
                red[wave - 1][gi][1][lane][0] = acc[gi][2];
                red[wave - 1][gi][1][lane][1] = acc[gi][3];
            }
        }
        __syncthreads();

        if (wave == 0) {
#pragma unroll
            for (int w = 0; w < 3; ++w)
#pragma unroll
                for (int gi = 0; gi < 4; ++gi) {
                    acc[gi][0] += red[w][gi][0][lane][0];
                    acc[gi][1] += red[w][gi][0][lane][1];
                    acc[gi][2] += red[w][gi][1][lane][0];
                    acc[gi][3] += red[w][gi][1][lane][1];
                }

#pragma unroll
            for (int r = 0; r < 4; ++r) {
                float gi_ = acc[0][r] + bsum[0];
                float gf_ = acc[1][r] + bsum[1];
                float go_ = acc[2][r] + bsum[2];
                float gz_ = acc[3][r] + bsum[3];
                float i_ = 1.f / (1.f + __expf(-gi_));
                float f_ = 1.f / (1.f + __expf(-gf_));
                float o_ = 1.f / (1.f + __expf(-go_));
                float z_ = 1.f - 2.f / (__expf(2.f * gz_) + 1.f);
                float c_ = i_ * z_ + f_ * cprev[r];
                cprev[r] = c_;
                float h_ = o_ * (1.f - 2.f / (__expf(2.f * c_) + 1.f));
                const int m = lq * 4 + r;                  // batch row within group
                out[(size_t)(rowbase + m) * (TT * HH) + (size_t)t * HH + col] = h_;
            }
            if (lane == 0) {
                // release: orders the out stores (L2 writeback) before the flag
                __hip_atomic_store(&flags[g * BLK_PER_G + j], t + 1,
                                   __ATOMIC_RELEASE, __HIP_MEMORY_SCOPE_AGENT);
            }
        }
        // waves 1..3 reuse `red` only after spinning past flags>=t+1, which
        // requires this block's wave0 release -> no extra barrier needed
    }
}

extern "C" void kernel_launch(void* const* d_in, const int* in_sizes, int n_in,
                              void* d_out, int out_size, void* d_ws, size_t ws_size,
                              hipStream_t stream) {
    const float* X   = (const float*)d_in[0];
    const float* Whi = (const float*)d_in[1];
    const float* Wxi = (const float*)d_in[2];
    const float* bi  = (const float*)d_in[3];
    const float* Whf = (const float*)d_in[4];
    const float* Wxf = (const float*)d_in[5];
    const float* bf  = (const float*)d_in[6];
    const float* Who = (const float*)d_in[7];
    const float* Wxo = (const float*)d_in[8];
    const float* bo  = (const float*)d_in[9];
    const float* Whz = (const float*)d_in[10];
    const float* Wxz = (const float*)d_in[11];
    const float* bz  = (const float*)d_in[12];
    float* out = (float*)d_out;

    int* flags = (int*)d_ws;   // NGROUP*BLK_PER_G*4 = 1 KB
    hipMemsetAsync(d_ws, 0, NGROUP * BLK_PER_G * sizeof(int), stream);

    // 256 blocks, 1 block/CU on 256 CUs -> all blocks resident by capacity;
    // hand-rolled flag sync, no cooperative launch needed.
    lstm_fused<<<dim3(256), dim3(256), 0, stream>>>(
        X, Whi, Wxi, bi, Whf, Wxf, bf, Who, Wxo, bo, Whz, Wxz, bz, out, flags);
}